// Round 2
// baseline (1121.391 us; speedup 1.0000x reference)
//
#include <hip/hip_runtime.h>
#include <hip/hip_fp16.h>

#define T_TOK 8192
#define H_DIM 1024
#define E_NUM 8
#define I_DIM 1408
#define NSLOT (2 * T_TOK)

typedef __attribute__((ext_vector_type(8))) _Float16 half8;
typedef __attribute__((ext_vector_type(4))) _Float16 half4v;
typedef __attribute__((ext_vector_type(4))) float f32x4;

// ---- static device buffers: persist across calls, fully rewritten each call ----
__device__ _Float16 g_x16[T_TOK * H_DIM];                  // x fp16 [T][H]
__device__ _Float16 g_w1t[E_NUM][2][I_DIM * H_DIM];        // [e][gate/up][n=i][k=h]
__device__ _Float16 g_sw1t[2][I_DIM * H_DIM];              // shared gate/up [i][h]
__device__ _Float16 g_w2t[E_NUM][H_DIM * I_DIM];           // [e][n=h][k=i]
__device__ _Float16 g_sw2t[H_DIM * I_DIM];                 // shared down [h][i]
__device__ _Float16 g_hbuf[(3 * T_TOK + 128) * I_DIM];     // SwiGLU activations
__device__ _Float16 g_dbuf[NSLOT * H_DIM];                 // routed down-proj (unweighted)

typedef const __attribute__((address_space(1))) unsigned int guint;
typedef __attribute__((address_space(3))) unsigned int luint;
__device__ __forceinline__ void gld16(void* l, const void* g) {
    __builtin_amdgcn_global_load_lds((guint*)g, (luint*)l, 16, 0, 0);
}

// ---------------- convert x: fp32 -> fp16, same layout ----------------
__global__ __launch_bounds__(256) void convert_x_kernel(const float* __restrict__ x)
{
    int i = (blockIdx.x * 256 + threadIdx.x) * 8;
    float4 v0 = *(const float4*)(x + i);
    float4 v1 = *(const float4*)(x + i + 4);
    half8 h = {(_Float16)v0.x, (_Float16)v0.y, (_Float16)v0.z, (_Float16)v0.w,
               (_Float16)v1.x, (_Float16)v1.y, (_Float16)v1.z, (_Float16)v1.w};
    *(half8*)&g_x16[i] = h;
}

// ---------------- transpose + convert: fp32 [R][C] -> fp16 [C][R] ----------------
__device__ __forceinline__ _Float16* dst_sel(int which, int z) {
    switch (which) {
        case 0: return g_w1t[z][0];
        case 1: return g_w1t[z][1];
        case 2: return g_w2t[z];
        case 3: return g_sw1t[0];
        case 4: return g_sw1t[1];
        default: return g_sw2t;
    }
}

__global__ __launch_bounds__(256) void transconv_kernel(
    const float* __restrict__ src, int which, int R, int C, size_t sstride)
{
    const float* s = src + (size_t)blockIdx.z * sstride;
    _Float16* d = dst_sel(which, blockIdx.z);
    int r0 = blockIdx.y * 64, c0 = blockIdx.x * 64;
    __shared__ float tile[64][65];
    int tr = threadIdx.x >> 4;
    int tc4 = (threadIdx.x & 15) * 4;
#pragma unroll
    for (int it = 0; it < 4; ++it) {
        int r = it * 16 + tr;
        float4 v = *(const float4*)(s + (size_t)(r0 + r) * C + c0 + tc4);
        tile[r][tc4] = v.x; tile[r][tc4 + 1] = v.y;
        tile[r][tc4 + 2] = v.z; tile[r][tc4 + 3] = v.w;
    }
    __syncthreads();
#pragma unroll
    for (int it = 0; it < 4; ++it) {
        int c = it * 16 + tr;  // output row = original column
        half4v h = {(_Float16)tile[tc4][c], (_Float16)tile[tc4 + 1][c],
                    (_Float16)tile[tc4 + 2][c], (_Float16)tile[tc4 + 3][c]};
        *(half4v*)&d[(size_t)(c0 + c) * R + r0 + tc4] = h;
    }
}

// ---------------- router: logits -> softmax -> top2 -> renorm ----------------
__global__ __launch_bounds__(64) void router_kernel(
    const float* __restrict__ x, const float* __restrict__ gw,
    int* __restrict__ cnt, int* __restrict__ tk_e, float* __restrict__ tk_w)
{
    const int t = blockIdx.x;
    const int lane = threadIdx.x;
    const float* xr = x + (size_t)t * H_DIM;
    float acc[8];
#pragma unroll
    for (int e = 0; e < 8; ++e) acc[e] = 0.f;
    for (int h4 = lane * 4; h4 < H_DIM; h4 += 256) {
        float4 xv = *(const float4*)(xr + h4);
        float xs[4] = {xv.x, xv.y, xv.z, xv.w};
#pragma unroll
        for (int j = 0; j < 4; ++j) {
            const float4* g4 = (const float4*)(gw + (size_t)(h4 + j) * 8);
            float4 ga = g4[0], gb = g4[1];
            acc[0] += xs[j] * ga.x; acc[1] += xs[j] * ga.y;
            acc[2] += xs[j] * ga.z; acc[3] += xs[j] * ga.w;
            acc[4] += xs[j] * gb.x; acc[5] += xs[j] * gb.y;
            acc[6] += xs[j] * gb.z; acc[7] += xs[j] * gb.w;
        }
    }
#pragma unroll
    for (int e = 0; e < 8; ++e) {
#pragma unroll
        for (int off = 32; off > 0; off >>= 1)
            acc[e] += __shfl_xor(acc[e], off, 64);
    }
    if (lane == 0) {
        float mx = acc[0];
#pragma unroll
        for (int e = 1; e < 8; ++e) mx = fmaxf(mx, acc[e]);
        float p[8], sum = 0.f;
#pragma unroll
        for (int e = 0; e < 8; ++e) { p[e] = __expf(acc[e] - mx); sum += p[e]; }
        float inv = 1.f / sum;
#pragma unroll
        for (int e = 0; e < 8; ++e) p[e] *= inv;
        int e0 = 0;
#pragma unroll
        for (int e = 1; e < 8; ++e) if (p[e] > p[e0]) e0 = e;
        int e1 = (e0 == 0) ? 1 : 0;
#pragma unroll
        for (int e = 0; e < 8; ++e) if (e != e0 && p[e] > p[e1]) e1 = e;
        float w0 = p[e0], w1 = p[e1];
        float invw = 1.f / (w0 + w1 + 1e-6f);
        tk_e[2 * t] = e0;          tk_e[2 * t + 1] = e1;
        tk_w[2 * t] = w0 * invw;   tk_w[2 * t + 1] = w1 * invw;
        atomicAdd(&cnt[e0], 1);
        atomicAdd(&cnt[e1], 1);
    }
}

__global__ void scan_kernel(const int* __restrict__ cnt, int* __restrict__ offs)
{
    if (threadIdx.x == 0) {
        int o = 0;
        for (int e = 0; e < 8; ++e) { offs[e] = o; o += cnt[e]; }
    }
}

__global__ __launch_bounds__(256) void scatter_kernel(
    const int* __restrict__ tk_e, const int* __restrict__ offs,
    int* __restrict__ fill, int* __restrict__ tokens, int* __restrict__ slotmap)
{
    int t = blockIdx.x * 256 + threadIdx.x;
    if (t >= T_TOK) return;
#pragma unroll
    for (int k = 0; k < 2; ++k) {
        int e = tk_e[2 * t + k];
        int s = atomicAdd(&fill[e], 1);
        int idx = offs[e] + s;
        tokens[idx] = t;
        slotmap[2 * t + k] = idx;
    }
}

// ---------------- GEMM1: h = silu(X Wg) * (X Wu) ----------------
// grid (m-tiles=64 fastest, n-tiles=22, p=9); p=0 shared over all tokens
__global__ __launch_bounds__(256) void gemm1_kernel(
    const int* __restrict__ cnt, const int* __restrict__ offs,
    const int* __restrict__ tokens)
{
    const int p = blockIdx.z;
    int count, rowbase;
    const _Float16 *Wg, *Wu;
    const int* tokptr = nullptr;
    if (p == 0) {
        count = T_TOK; rowbase = 0; Wg = g_sw1t[0]; Wu = g_sw1t[1];
    } else {
        int e = p - 1;
        count = cnt[e];
        int ob = offs[e];
        rowbase = T_TOK + ob;
        tokptr = tokens + ob;
        Wg = g_w1t[e][0]; Wu = g_w1t[e][1];
    }
    const int m0 = blockIdx.x * 128;
    if (m0 >= count) return;
    const int n0 = blockIdx.y * 64;
    const int tid = threadIdx.x;

    __shared__ _Float16 Asm[128 * 32];
    __shared__ _Float16 Bg[64 * 32];
    __shared__ _Float16 Bu[64 * 32];
    __shared__ int toksm[128];

    if (tid < 128) {
        int s = m0 + tid;
        int t;
        if (p == 0) t = (s < count) ? s : 0;
        else        t = (s < count) ? tokptr[s] : tokptr[0];
        toksm[tid] = t;
    }
    __syncthreads();

    // staging addresses: chunk C -> m = C>>2, k-chunk = (C&3)*8; LDS dest = C*16B
    const int kc = (tid & 3) * 8;
    const _Float16* pa0 = g_x16 + (size_t)toksm[tid >> 2] * H_DIM + kc;
    const _Float16* pa1 = g_x16 + (size_t)toksm[(256 + tid) >> 2] * H_DIM + kc;
    const int nB = tid >> 2;
    const _Float16* pbg = Wg + (size_t)(n0 + nB) * H_DIM + kc;
    const _Float16* pbu = Wu + (size_t)(n0 + nB) * H_DIM + kc;

    const int wid = tid >> 6, lane = tid & 63;
    const int wm = (wid >> 1) * 64, wn = (wid & 1) * 32;
    const int quad = lane >> 4, l16 = lane & 15;

    char* lA0 = (char*)Asm + (size_t)(wid * 64) * 16;
    char* lA1 = (char*)Asm + (size_t)(256 + wid * 64) * 16;
    char* lBg = (char*)Bg + (size_t)(wid * 64) * 16;
    char* lBu = (char*)Bu + (size_t)(wid * 64) * 16;

    f32x4 zero4 = {0.f, 0.f, 0.f, 0.f};
    f32x4 accg[4][2], accu[4][2];
#pragma unroll
    for (int mt = 0; mt < 4; ++mt)
#pragma unroll
        for (int nt = 0; nt < 2; ++nt) { accg[mt][nt] = zero4; accu[mt][nt] = zero4; }

    for (int k0 = 0; k0 < H_DIM; k0 += 32) {
        gld16(lA0, pa0 + k0);
        gld16(lA1, pa1 + k0);
        gld16(lBg, pbg + k0);
        gld16(lBu, pbu + k0);
        __syncthreads();

        half8 a[4], bg2[2], bu2[2];
#pragma unroll
        for (int mt = 0; mt < 4; ++mt)
            a[mt] = *(const half8*)&Asm[(wm + mt * 16 + l16) * 32 + quad * 8];
#pragma unroll
        for (int nt = 0; nt < 2; ++nt) {
            bg2[nt] = *(const half8*)&Bg[(wn + nt * 16 + l16) * 32 + quad * 8];
            bu2[nt] = *(const half8*)&Bu[(wn + nt * 16 + l16) * 32 + quad * 8];
        }
#pragma unroll
        for (int mt = 0; mt < 4; ++mt)
#pragma unroll
            for (int nt = 0; nt < 2; ++nt) {
                accg[mt][nt] = __builtin_amdgcn_mfma_f32_16x16x32_f16(a[mt], bg2[nt], accg[mt][nt], 0, 0, 0);
                accu[mt][nt] = __builtin_amdgcn_mfma_f32_16x16x32_f16(a[mt], bu2[nt], accu[mt][nt], 0, 0, 0);
            }
        __syncthreads();
    }

#pragma unroll
    for (int mt = 0; mt < 4; ++mt) {
#pragma unroll
        for (int nt = 0; nt < 2; ++nt) {
            int icol = n0 + wn + nt * 16 + l16;
#pragma unroll
            for (int rg = 0; rg < 4; ++rg) {
                int s = m0 + wm + mt * 16 + quad * 4 + rg;
                if (s < count) {
                    float g = accg[mt][nt][rg];
                    float u = accu[mt][nt][rg];
                    float hval = (g / (1.f + __expf(-g))) * u;
                    g_hbuf[(size_t)(rowbase + s) * I_DIM + icol] = (_Float16)hval;
                }
            }
        }
    }
}

// ---------------- GEMM2: shared -> out directly; routed -> dbuf (unweighted) ----------------
// grid (m-tiles=64 fastest, n-tiles=8, p=9)
__global__ __launch_bounds__(256) void gemm2_kernel(
    const int* __restrict__ cnt, const int* __restrict__ offs, float* __restrict__ out)
{
    const int p = blockIdx.z;
    int count, hrow, drow = 0;
    const _Float16* W;
    if (p == 0) { count = T_TOK; hrow = 0; W = g_sw2t; }
    else {
        int e = p - 1;
        count = cnt[e];
        int ob = offs[e];
        hrow = T_TOK + ob; drow = ob;
        W = g_w2t[e];
    }
    const int m0 = blockIdx.x * 128;
    if (m0 >= count) return;
    const int n0 = blockIdx.y * 128;
    const int tid = threadIdx.x;

    __shared__ _Float16 Asm[128 * 32];
    __shared__ _Float16 Bsm[128 * 32];

    const int kc = (tid & 3) * 8;
    const _Float16* pa0 = g_hbuf + (size_t)(hrow + m0 + (tid >> 2)) * I_DIM + kc;
    const _Float16* pa1 = g_hbuf + (size_t)(hrow + m0 + ((256 + tid) >> 2)) * I_DIM + kc;
    const _Float16* pb0 = W + (size_t)(n0 + (tid >> 2)) * I_DIM + kc;
    const _Float16* pb1 = W + (size_t)(n0 + ((256 + tid) >> 2)) * I_DIM + kc;

    const int wid = tid >> 6, lane = tid & 63;
    const int wm = (wid >> 1) * 64, wn = (wid & 1) * 64;
    const int quad = lane >> 4, l16 = lane & 15;

    char* lA0 = (char*)Asm + (size_t)(wid * 64) * 16;
    char* lA1 = (char*)Asm + (size_t)(256 + wid * 64) * 16;
    char* lB0 = (char*)Bsm + (size_t)(wid * 64) * 16;
    char* lB1 = (char*)Bsm + (size_t)(256 + wid * 64) * 16;

    f32x4 zero4 = {0.f, 0.f, 0.f, 0.f};
    f32x4 acc[4][4];
#pragma unroll
    for (int mt = 0; mt < 4; ++mt)
#pragma unroll
        for (int nt = 0; nt < 4; ++nt) acc[mt][nt] = zero4;

    for (int k0 = 0; k0 < I_DIM; k0 += 32) {
        gld16(lA0, pa0 + k0);
        gld16(lA1, pa1 + k0);
        gld16(lB0, pb0 + k0);
        gld16(lB1, pb1 + k0);
        __syncthreads();

        half8 a[4], b[4];
#pragma unroll
        for (int mt = 0; mt < 4; ++mt)
            a[mt] = *(const half8*)&Asm[(wm + mt * 16 + l16) * 32 + quad * 8];
#pragma unroll
        for (int nt = 0; nt < 4; ++nt)
            b[nt] = *(const half8*)&Bsm[(wn + nt * 16 + l16) * 32 + quad * 8];
#pragma unroll
        for (int mt = 0; mt < 4; ++mt)
#pragma unroll
            for (int nt = 0; nt < 4; ++nt)
                acc[mt][nt] = __builtin_amdgcn_mfma_f32_16x16x32_f16(a[mt], b[nt], acc[mt][nt], 0, 0, 0);
        __syncthreads();
    }

#pragma unroll
    for (int mt = 0; mt < 4; ++mt) {
#pragma unroll
        for (int nt = 0; nt < 4; ++nt) {
            int col = n0 + wn + nt * 16 + l16;
#pragma unroll
            for (int rg = 0; rg < 4; ++rg) {
                int s = m0 + wm + mt * 16 + quad * 4 + rg;
                if (s < count) {
                    float v = acc[mt][nt][rg];
                    if (p == 0) out[(size_t)s * H_DIM + col] = v;
                    else        g_dbuf[(size_t)(drow + s) * H_DIM + col] = (_Float16)v;
                }
            }
        }
    }
}

// ---------------- combine: out[t] += w0*dbuf[s0] + w1*dbuf[s1] ----------------
__global__ __launch_bounds__(256) void combine_kernel(
    const int* __restrict__ slotmap, const float* __restrict__ tk_w,
    float* __restrict__ out)
{
    int t = blockIdx.x;
    int c = threadIdx.x * 4;
    int s0 = slotmap[2 * t], s1 = slotmap[2 * t + 1];
    float w0 = tk_w[2 * t], w1 = tk_w[2 * t + 1];
    float4 o = *(float4*)(out + (size_t)t * H_DIM + c);
    half4v d0 = *(const half4v*)&g_dbuf[(size_t)s0 * H_DIM + c];
    half4v d1 = *(const half4v*)&g_dbuf[(size_t)s1 * H_DIM + c];
    o.x += w0 * (float)d0[0] + w1 * (float)d1[0];
    o.y += w0 * (float)d0[1] + w1 * (float)d1[1];
    o.z += w0 * (float)d0[2] + w1 * (float)d1[2];
    o.w += w0 * (float)d0[3] + w1 * (float)d1[3];
    *(float4*)(out + (size_t)t * H_DIM + c) = o;
}

// ---------------- launch ----------------
extern "C" void kernel_launch(void* const* d_in, const int* in_sizes, int n_in,
                              void* d_out, int out_size, void* d_ws, size_t ws_size,
                              hipStream_t stream)
{
    const float* x  = (const float*)d_in[0];
    const float* gw = (const float*)d_in[1];
    const float* eg = (const float*)d_in[2];
    const float* eu = (const float*)d_in[3];
    const float* ed = (const float*)d_in[4];
    const float* sg = (const float*)d_in[5];
    const float* su = (const float*)d_in[6];
    const float* sd = (const float*)d_in[7];
    float* out = (float*)d_out;

    char* ws = (char*)d_ws;
    int* cnt     = (int*)(ws + 0);
    int* fill    = (int*)(ws + 32);
    int* offs    = (int*)(ws + 64);
    int* tk_e    = (int*)(ws + 128);
    float* tk_w  = (float*)(ws + 128 + 1 * 65536);
    int* tokens  = (int*)(ws + 128 + 2 * 65536);
    int* slotmap = (int*)(ws + 128 + 3 * 65536);

    hipMemsetAsync(ws, 0, 96, stream);

    router_kernel<<<T_TOK, 64, 0, stream>>>(x, gw, cnt, tk_e, tk_w);
    scan_kernel<<<1, 64, 0, stream>>>(cnt, offs);
    scatter_kernel<<<T_TOK / 256, 256, 0, stream>>>(tk_e, offs, fill, tokens, slotmap);

    convert_x_kernel<<<T_TOK * H_DIM / (256 * 8), 256, 0, stream>>>(x);
    // eg/eu: [H][I] -> [I][H] per expert
    transconv_kernel<<<dim3(I_DIM / 64, H_DIM / 64, E_NUM), 256, 0, stream>>>(
        eg, 0, H_DIM, I_DIM, (size_t)H_DIM * I_DIM);
    transconv_kernel<<<dim3(I_DIM / 64, H_DIM / 64, E_NUM), 256, 0, stream>>>(
        eu, 1, H_DIM, I_DIM, (size_t)H_DIM * I_DIM);
    // ed: [I][H] -> [H][I] per expert
    transconv_kernel<<<dim3(H_DIM / 64, I_DIM / 64, E_NUM), 256, 0, stream>>>(
        ed, 2, I_DIM, H_DIM, (size_t)I_DIM * H_DIM);
    transconv_kernel<<<dim3(I_DIM / 64, H_DIM / 64, 1), 256, 0, stream>>>(
        sg, 3, H_DIM, I_DIM, 0);
    transconv_kernel<<<dim3(I_DIM / 64, H_DIM / 64, 1), 256, 0, stream>>>(
        su, 4, H_DIM, I_DIM, 0);
    transconv_kernel<<<dim3(H_DIM / 64, I_DIM / 64, 1), 256, 0, stream>>>(
        sd, 5, I_DIM, H_DIM, 0);

    gemm1_kernel<<<dim3(T_TOK / 128, I_DIM / 64, 9), 256, 0, stream>>>(cnt, offs, tokens);
    gemm2_kernel<<<dim3(T_TOK / 128, H_DIM / 128, 9), 256, 0, stream>>>(cnt, offs, out);
    combine_kernel<<<T_TOK, 256, 0, stream>>>(slotmap, tk_w, out);
}